// Round 1
// baseline (140.345 us; speedup 1.0000x reference)
//
#include <hip/hip_runtime.h>
#include <stdint.h>

#define N 4096
#define D 512
#define NHALF 8388608u   // N*N/2
#define MARGIN_F 2.0f
#define EPS_F 1e-11f

// Exact JAX threefry2x32 with key (0,1)  [jax.random.key(1) -> data (0,1)]
__device__ __forceinline__ void threefry2x32_01(uint32_t& x0, uint32_t& x1) {
    const uint32_t ks0 = 0u, ks1 = 1u, ks2 = 0x1BD11BDBu; // 0x1BD11BDA ^ 0 ^ 1
    x0 += ks0; x1 += ks1;
#define TF_R(R) { x0 += x1; x1 = (x1 << (R)) | (x1 >> (32 - (R))); x1 ^= x0; }
    TF_R(13) TF_R(15) TF_R(26) TF_R(6)
    x0 += ks1; x1 += ks2 + 1u;
    TF_R(17) TF_R(29) TF_R(16) TF_R(24)
    x0 += ks2; x1 += ks0 + 2u;
    TF_R(13) TF_R(15) TF_R(26) TF_R(6)
    x0 += ks0; x1 += ks1 + 3u;
    TF_R(17) TF_R(29) TF_R(16) TF_R(24)
    x0 += ks1; x1 += ks2 + 4u;
    TF_R(13) TF_R(15) TF_R(26) TF_R(6)
    x0 += ks2; x1 += ks0 + 5u;
#undef TF_R
}

__device__ __forceinline__ void argmax_combine(uint32_t& v, int& j, uint32_t ov, int oj) {
    // larger value wins; exact tie -> smaller index (matches jnp.argmax first-index)
    if (ov > v || (ov == v && oj < j)) { v = ov; j = oj; }
}

// K1: sq[r] = sum_k F[r][k]^2 ; one wave per row
__global__ void k_sq(const float* __restrict__ F, float* __restrict__ sq) {
    int t = threadIdx.x, w = t >> 6, lane = t & 63;
    int r = blockIdx.x * 4 + w;
    const float4* fr = (const float4*)(F + (size_t)r * D);
    float4 a = fr[lane * 2], b = fr[lane * 2 + 1];
    float s = a.x*a.x + a.y*a.y + a.z*a.z + a.w*a.w
            + b.x*b.x + b.y*b.y + b.z*b.z + b.w*b.w;
    for (int m = 32; m; m >>= 1) s += __shfl_xor(s, m, 64);
    if (lane == 0) sq[r] = s;
}

// K2: neg_idx via exact threefry gumbel-argmax (integer-monotone shortcut).
// Block i0 handles rows i0 and i0+2048 (threefry pair outputs).
__global__ void k_negidx(const int* __restrict__ labels, int* __restrict__ neg_idx) {
    int i0 = blockIdx.x;
    int t = threadIdx.x;
    int lab0 = labels[i0], lab1 = labels[i0 + 2048];
    uint32_t v0 = 0u, v1 = 0u;
    int j0 = 0x7fffffff, j1 = 0x7fffffff;
    bool h0 = false, h1 = false;
    for (int j = t; j < N; j += 256) {
        uint32_t p = (uint32_t)(i0 * N + j);
        uint32_t x0 = p, x1 = p + NHALF;
        threefry2x32_01(x0, x1);
        uint32_t b0 = x0 >> 9, b1 = x1 >> 9;   // 23-bit uniform draw (monotone in gumbel)
        int lj = labels[j];
        if (lj != lab0) { if (!h0 || b0 > v0) { v0 = b0; j0 = j; h0 = true; } }
        if (lj != lab1) { if (!h1 || b1 > v1) { v1 = b1; j1 = j; h1 = true; } }
    }
    // wave butterfly reduce (invalid = v=0, j=INT_MAX loses to any valid)
    for (int m = 32; m; m >>= 1) {
        uint32_t ov = __shfl_xor(v0, m, 64); int oj = __shfl_xor(j0, m, 64);
        argmax_combine(v0, j0, ov, oj);
        ov = __shfl_xor(v1, m, 64); oj = __shfl_xor(j1, m, 64);
        argmax_combine(v1, j1, ov, oj);
    }
    __shared__ uint32_t sv0[4], sv1[4];
    __shared__ int sj0[4], sj1[4];
    int w = t >> 6, lane = t & 63;
    if (lane == 0) { sv0[w] = v0; sj0[w] = j0; sv1[w] = v1; sj1[w] = j1; }
    __syncthreads();
    if (t == 0) {
        uint32_t bv = sv0[0]; int bj = sj0[0];
        for (int k = 1; k < 4; k++) argmax_combine(bv, bj, sv0[k], sj0[k]);
        neg_idx[i0] = (bj == 0x7fffffff) ? -1 : bj;
        bv = sv1[0]; bj = sj1[0];
        for (int k = 1; k < 4; k++) argmax_combine(bv, bj, sv1[k], sj1[k]);
        neg_idx[i0 + 2048] = (bj == 0x7fffffff) ? -1 : bj;
    }
}

// K3: neg_dist[r] = sqrt(max(sq[r]+sq[neg]-2*dot, EPS)) ; one wave per row
__global__ void k_negdist(const float* __restrict__ F, const float* __restrict__ sq,
                          const int* __restrict__ neg_idx, float* __restrict__ neg_dist) {
    int t = threadIdx.x, w = t >> 6, lane = t & 63;
    int r = blockIdx.x * 4 + w;
    int jn = neg_idx[r];
    if (jn < 0) { if (lane == 0) neg_dist[r] = 0.f; return; }
    const float4* fr = (const float4*)(F + (size_t)r * D);
    const float4* fj = (const float4*)(F + (size_t)jn * D);
    float4 a0 = fr[lane*2], a1 = fr[lane*2+1];
    float4 b0 = fj[lane*2], b1 = fj[lane*2+1];
    float d = a0.x*b0.x + a0.y*b0.y + a0.z*b0.z + a0.w*b0.w
            + a1.x*b1.x + a1.y*b1.y + a1.z*b1.z + a1.w*b1.w;
    for (int m = 32; m; m >>= 1) d += __shfl_xor(d, m, 64);
    if (lane == 0) neg_dist[r] = sqrtf(fmaxf(sq[r] + sq[jn] - 2.f * d, EPS_F));
}

// K4: sum over same-label pairs (j>i) of max(margin + dist_ij - neg_dist_i, 0)
__global__ void k_loss(const float* __restrict__ F, const int* __restrict__ labels,
                       const float* __restrict__ sq, const int* __restrict__ neg_idx,
                       const float* __restrict__ neg_dist, float* __restrict__ acc) {
    int i = blockIdx.x;
    __shared__ float fi[D];
    __shared__ float wtot[4];
    __shared__ int wcnt[4];
    int t = threadIdx.x, w = t >> 6, lane = t & 63;
    // stage row i (vectorized: 256 threads x 2 floats)
    ((float2*)fi)[t] = ((const float2*)(F + (size_t)i * D))[t];
    int myLab = labels[i];
    bool hasneg = neg_idx[i] >= 0;
    float ndist = hasneg ? neg_dist[i] : 0.f;
    float sqi = sq[i];
    __syncthreads();
    float tot = 0.f; int cnt = 0;
    if (hasneg) {
        for (int base = i + 1 + w * 64; base < N; base += 256) {
            int j = base + lane;
            int lj = (j < N) ? labels[j] : -1;
            uint64_t mask = __ballot(lj == myLab);
            while (mask) {
                int b = __ffsll((unsigned long long)mask) - 1;
                mask &= mask - 1;
                int jj = base + b;
                const float4* fj = (const float4*)(F + (size_t)jj * D);
                float4 a0 = fj[lane*2], a1 = fj[lane*2+1];
                float4 b0 = *(const float4*)(&fi[lane*8]);
                float4 b1 = *(const float4*)(&fi[lane*8+4]);
                float d = a0.x*b0.x + a0.y*b0.y + a0.z*b0.z + a0.w*b0.w
                        + a1.x*b1.x + a1.y*b1.y + a1.z*b1.z + a1.w*b1.w;
                for (int m = 32; m; m >>= 1) d += __shfl_xor(d, m, 64);
                float dist = sqrtf(fmaxf(sqi + sq[jj] - 2.f * d, EPS_F));
                tot += fmaxf(MARGIN_F + dist - ndist, 0.f);
                cnt++;
            }
        }
    }
    if (lane == 0) { wtot[w] = tot; wcnt[w] = cnt; }
    __syncthreads();
    if (t == 0) {
        float T = wtot[0] + wtot[1] + wtot[2] + wtot[3];
        int   C = wcnt[0] + wcnt[1] + wcnt[2] + wcnt[3];
        if (C > 0) {
            atomicAdd(&acc[0], T);
            atomicAdd(&acc[1], (float)C);
        }
    }
}

__global__ void k_final(const float* __restrict__ acc, float* __restrict__ out) {
    if (threadIdx.x == 0)
        out[0] = (acc[1] > 0.f) ? (acc[0] / acc[1]) : 0.f;
}

extern "C" void kernel_launch(void* const* d_in, const int* in_sizes, int n_in,
                              void* d_out, int out_size, void* d_ws, size_t ws_size,
                              hipStream_t stream) {
    const float* F      = (const float*)d_in[0];
    const int*   labels = (const int*)d_in[1];
    float* out = (float*)d_out;

    // workspace layout
    float* sq       = (float*)d_ws;                      // 4096 f
    int*   neg_idx  = (int*)((char*)d_ws + 16384);       // 4096 i
    float* neg_dist = (float*)((char*)d_ws + 32768);     // 4096 f
    float* acc      = (float*)((char*)d_ws + 49152);     // 2 f

    hipMemsetAsync(acc, 0, 2 * sizeof(float), stream);

    k_sq     <<<N / 4, 256, 0, stream>>>(F, sq);
    k_negidx <<<N / 2, 256, 0, stream>>>(labels, neg_idx);
    k_negdist<<<N / 4, 256, 0, stream>>>(F, sq, neg_idx, neg_dist);
    k_loss   <<<N,     256, 0, stream>>>(F, labels, sq, neg_idx, neg_dist, acc);
    k_final  <<<1,      64, 0, stream>>>(acc, out);
}

// Round 2
// 72.898 us; speedup vs baseline: 1.9252x; 1.9252x over previous
//
#include <hip/hip_runtime.h>
#include <stdint.h>

#define N 4096
#define D 512
#define L 512
#define NHALF 8388608u   // N*N/2
#define MARGIN_F 2.0f
#define EPS_F 1e-11f

// Exact JAX threefry2x32 with key (0,1)  [jax.random.key(1) -> data (0,1)]
__device__ __forceinline__ void threefry2x32_01(uint32_t& x0, uint32_t& x1) {
    const uint32_t ks0 = 0u, ks1 = 1u, ks2 = 0x1BD11BDBu; // 0x1BD11BDA ^ 0 ^ 1
    x0 += ks0; x1 += ks1;
#define TF_R(R) { x0 += x1; x1 = (x1 << (R)) | (x1 >> (32 - (R))); x1 ^= x0; }
    TF_R(13) TF_R(15) TF_R(26) TF_R(6)
    x0 += ks1; x1 += ks2 + 1u;
    TF_R(17) TF_R(29) TF_R(16) TF_R(24)
    x0 += ks2; x1 += ks0 + 2u;
    TF_R(13) TF_R(15) TF_R(26) TF_R(6)
    x0 += ks0; x1 += ks1 + 3u;
    TF_R(17) TF_R(29) TF_R(16) TF_R(24)
    x0 += ks1; x1 += ks2 + 4u;
    TF_R(13) TF_R(15) TF_R(26) TF_R(6)
    x0 += ks2; x1 += ks0 + 5u;
#undef TF_R
}

__device__ __forceinline__ void argmax_combine(uint32_t& v, int& j, uint32_t ov, int oj) {
    // larger value wins; exact tie -> smaller index (matches jnp.argmax first-index)
    if (ov > v || (ov == v && oj < j)) { v = ov; j = oj; }
}

// K1: sq[r] = sum_k F[r][k]^2 ; one wave per row
__global__ void k_sq(const float* __restrict__ F, float* __restrict__ sq) {
    int t = threadIdx.x, w = t >> 6, lane = t & 63;
    int r = blockIdx.x * 4 + w;
    const float4* fr = (const float4*)(F + (size_t)r * D);
    float4 a = fr[lane * 2], b = fr[lane * 2 + 1];
    float s = a.x*a.x + a.y*a.y + a.z*a.z + a.w*a.w
            + b.x*b.x + b.y*b.y + b.z*b.z + b.w*b.w;
    for (int m = 32; m; m >>= 1) s += __shfl_xor(s, m, 64);
    if (lane == 0) sq[r] = s;
}

// K2: bucket rows by label (CSR) — single block, 512 threads
__global__ void k_bucket(const int* __restrict__ labels,
                         int* __restrict__ offsets, int* __restrict__ rows_buf) {
    __shared__ int hist[L];
    __shared__ int base[L];
    __shared__ int sa[L], sb[L];
    int t = threadIdx.x;  // 512 threads
    hist[t] = 0;
    __syncthreads();
    for (int i = t; i < N; i += L) atomicAdd(&hist[labels[i]], 1);
    __syncthreads();
    sa[t] = hist[t];
    __syncthreads();
    int* src = sa; int* dst = sb;
    for (int off = 1; off < L; off <<= 1) {
        dst[t] = src[t] + ((t >= off) ? src[t - off] : 0);
        __syncthreads();
        int* tmp = src; src = dst; dst = tmp;
    }
    offsets[t + 1] = src[t];
    if (t == 0) offsets[0] = 0;
    base[t] = src[t] - hist[t];
    __syncthreads();
    hist[t] = 0;  // reuse as cursor
    __syncthreads();
    for (int i = t; i < N; i += L) {
        int l = labels[i];
        int pos = atomicAdd(&hist[l], 1);
        rows_buf[base[l] + pos] = i;
    }
}

// K3: neg_idx via exact threefry gumbel-argmax (integer-monotone shortcut).
// Block i0 handles rows i0 and i0+2048 (threefry pair outputs).
__global__ void k_negidx(const int* __restrict__ labels, int* __restrict__ neg_idx) {
    int i0 = blockIdx.x;
    int t = threadIdx.x;
    int lab0 = labels[i0], lab1 = labels[i0 + 2048];
    uint32_t v0 = 0u, v1 = 0u;
    int j0 = 0x7fffffff, j1 = 0x7fffffff;
    bool h0 = false, h1 = false;
    for (int j = t; j < N; j += 256) {
        uint32_t p = (uint32_t)(i0 * N + j);
        uint32_t x0 = p, x1 = p + NHALF;
        threefry2x32_01(x0, x1);
        uint32_t b0 = x0 >> 9, b1 = x1 >> 9;   // 23-bit uniform draw (monotone in gumbel)
        int lj = labels[j];
        if (lj != lab0) { if (!h0 || b0 > v0) { v0 = b0; j0 = j; h0 = true; } }
        if (lj != lab1) { if (!h1 || b1 > v1) { v1 = b1; j1 = j; h1 = true; } }
    }
    for (int m = 32; m; m >>= 1) {
        uint32_t ov = __shfl_xor(v0, m, 64); int oj = __shfl_xor(j0, m, 64);
        argmax_combine(v0, j0, ov, oj);
        ov = __shfl_xor(v1, m, 64); oj = __shfl_xor(j1, m, 64);
        argmax_combine(v1, j1, ov, oj);
    }
    __shared__ uint32_t sv0[4], sv1[4];
    __shared__ int sj0[4], sj1[4];
    int w = t >> 6, lane = t & 63;
    if (lane == 0) { sv0[w] = v0; sj0[w] = j0; sv1[w] = v1; sj1[w] = j1; }
    __syncthreads();
    if (t == 0) {
        uint32_t bv = sv0[0]; int bj = sj0[0];
        for (int k = 1; k < 4; k++) argmax_combine(bv, bj, sv0[k], sj0[k]);
        neg_idx[i0] = (bj == 0x7fffffff) ? -1 : bj;
        bv = sv1[0]; bj = sj1[0];
        for (int k = 1; k < 4; k++) argmax_combine(bv, bj, sv1[k], sj1[k]);
        neg_idx[i0 + 2048] = (bj == 0x7fffffff) ? -1 : bj;
    }
}

// K4: neg_dist[r] = sqrt(max(sq[r]+sq[neg]-2*dot, EPS)) ; one wave per row
__global__ void k_negdist(const float* __restrict__ F, const float* __restrict__ sq,
                          const int* __restrict__ neg_idx, float* __restrict__ neg_dist) {
    int t = threadIdx.x, w = t >> 6, lane = t & 63;
    int r = blockIdx.x * 4 + w;
    int jn = neg_idx[r];
    if (jn < 0) { if (lane == 0) neg_dist[r] = 0.f; return; }
    const float4* fr = (const float4*)(F + (size_t)r * D);
    const float4* fj = (const float4*)(F + (size_t)jn * D);
    float4 a0 = fr[lane*2], a1 = fr[lane*2+1];
    float4 b0 = fj[lane*2], b1 = fj[lane*2+1];
    float d = a0.x*b0.x + a0.y*b0.y + a0.z*b0.z + a0.w*b0.w
            + a1.x*b1.x + a1.y*b1.y + a1.z*b1.z + a1.w*b1.w;
    for (int m = 32; m; m >>= 1) d += __shfl_xor(d, m, 64);
    if (lane == 0) neg_dist[r] = sqrtf(fmaxf(sq[r] + sq[jn] - 2.f * d, EPS_F));
}

// K5: per-label pair enumeration. One block per label, 4 waves round-robin pairs.
__global__ void k_pairs(const float* __restrict__ F,
                        const int* __restrict__ offsets, const int* __restrict__ rows_buf,
                        const float* __restrict__ sq, const int* __restrict__ neg_idx,
                        const float* __restrict__ neg_dist, float* __restrict__ acc) {
    int l = blockIdx.x;
    int t = threadIdx.x, w = t >> 6, lane = t & 63;
    int beg = offsets[l], end = offsets[l + 1];
    int c = end - beg;
    if (c < 2) return;
    float tot = 0.f; int cnt = 0;
    int pidx = 0;
    for (int a = 0; a < c - 1; a++) {
        int ra = rows_buf[beg + a];
        for (int b = a + 1; b < c; b++, pidx++) {
            if ((pidx & 3) != w) continue;          // wave-uniform
            int rb = rows_buf[beg + b];
            int i = min(ra, rb), j = max(ra, rb);   // anchor = smaller row index
            if (neg_idx[i] < 0) continue;           // wave-uniform
            const float4* fi = (const float4*)(F + (size_t)i * D);
            const float4* fj = (const float4*)(F + (size_t)j * D);
            float4 x0 = fi[lane*2], x1 = fi[lane*2+1];
            float4 y0 = fj[lane*2], y1 = fj[lane*2+1];
            float d = x0.x*y0.x + x0.y*y0.y + x0.z*y0.z + x0.w*y0.w
                    + x1.x*y1.x + x1.y*y1.y + x1.z*y1.z + x1.w*y1.w;
            for (int m = 32; m; m >>= 1) d += __shfl_xor(d, m, 64);
            float dist = sqrtf(fmaxf(sq[i] + sq[j] - 2.f * d, EPS_F));
            tot += fmaxf(MARGIN_F + dist - neg_dist[i], 0.f);
            cnt++;
        }
    }
    __shared__ float wtot[4];
    __shared__ int wcnt[4];
    if (lane == 0) { wtot[w] = tot; wcnt[w] = cnt; }
    __syncthreads();
    if (t == 0) {
        float T = wtot[0] + wtot[1] + wtot[2] + wtot[3];
        int   C = wcnt[0] + wcnt[1] + wcnt[2] + wcnt[3];
        if (C > 0) {
            atomicAdd(&acc[0], T);
            atomicAdd(&acc[1], (float)C);
        }
    }
}

__global__ void k_final(const float* __restrict__ acc, float* __restrict__ out) {
    if (threadIdx.x == 0)
        out[0] = (acc[1] > 0.f) ? (acc[0] / acc[1]) : 0.f;
}

extern "C" void kernel_launch(void* const* d_in, const int* in_sizes, int n_in,
                              void* d_out, int out_size, void* d_ws, size_t ws_size,
                              hipStream_t stream) {
    const float* F      = (const float*)d_in[0];
    const int*   labels = (const int*)d_in[1];
    float* out = (float*)d_out;

    // workspace layout
    float* sq       = (float*)d_ws;                        // 4096 f   @ 0
    int*   neg_idx  = (int*)((char*)d_ws + 16384);         // 4096 i   @ 16K
    float* neg_dist = (float*)((char*)d_ws + 32768);       // 4096 f   @ 32K
    int*   offsets  = (int*)((char*)d_ws + 49152);         // 513 i    @ 48K
    int*   rows_buf = (int*)((char*)d_ws + 53248);         // 4096 i   @ 52K
    float* acc      = (float*)((char*)d_ws + 69632);       // 2 f      @ 68K

    hipMemsetAsync(acc, 0, 2 * sizeof(float), stream);

    k_sq     <<<N / 4, 256, 0, stream>>>(F, sq);
    k_bucket <<<1,     512, 0, stream>>>(labels, offsets, rows_buf);
    k_negidx <<<N / 2, 256, 0, stream>>>(labels, neg_idx);
    k_negdist<<<N / 4, 256, 0, stream>>>(F, sq, neg_idx, neg_dist);
    k_pairs  <<<L,     256, 0, stream>>>(F, offsets, rows_buf, sq, neg_idx, neg_dist, acc);
    k_final  <<<1,      64, 0, stream>>>(acc, out);
}

// Round 4
// 69.649 us; speedup vs baseline: 2.0150x; 1.0467x over previous
//
#include <hip/hip_runtime.h>
#include <stdint.h>

#define N 4096
#define D 512
#define L 512
#define NHALF 8388608u   // N*N/2
#define MARGIN_F 2.0f
#define EPS_F 1e-11f
#define MAXB 64          // max bucket size (mean 8, binomial tail << 64)

// Exact JAX threefry2x32 with key (0,1)  [jax.random.key(1) -> data (0,1)]
__device__ __forceinline__ void threefry2x32_01(uint32_t& x0, uint32_t& x1) {
    const uint32_t ks0 = 0u, ks1 = 1u, ks2 = 0x1BD11BDBu; // 0x1BD11BDA ^ 0 ^ 1
    x0 += ks0; x1 += ks1;
#define TF_R(R) { x0 += x1; x1 = (x1 << (R)) | (x1 >> (32 - (R))); x1 ^= x0; }
    TF_R(13) TF_R(15) TF_R(26) TF_R(6)
    x0 += ks1; x1 += ks2 + 1u;
    TF_R(17) TF_R(29) TF_R(16) TF_R(24)
    x0 += ks2; x1 += ks0 + 2u;
    TF_R(13) TF_R(15) TF_R(26) TF_R(6)
    x0 += ks0; x1 += ks1 + 3u;
    TF_R(17) TF_R(29) TF_R(16) TF_R(24)
    x0 += ks1; x1 += ks2 + 4u;
    TF_R(13) TF_R(15) TF_R(26) TF_R(6)
    x0 += ks2; x1 += ks0 + 5u;
#undef TF_R
}

__device__ __forceinline__ void argmax_combine(uint32_t& v, int& j, uint32_t ov, int oj) {
    // larger value wins; exact tie -> smaller index (matches jnp.argmax first-index)
    if (ov > v || (ov == v && oj < j)) { v = ov; j = oj; }
}

__device__ __forceinline__ float wave_dot(const float4* __restrict__ a,
                                          const float4* __restrict__ b, int lane) {
    float4 x0 = a[lane*2], x1 = a[lane*2+1];
    float4 y0 = b[lane*2], y1 = b[lane*2+1];
    float d = x0.x*y0.x + x0.y*y0.y + x0.z*y0.z + x0.w*y0.w
            + x1.x*y1.x + x1.y*y1.y + x1.z*y1.z + x1.w*y1.w;
    for (int m = 32; m; m >>= 1) d += __shfl_xor(d, m, 64);
    return d;
}

// K1 (fused): zero acc, row sum-squares, threefry gumbel-argmax neg_idx.
// Block i0 in [0,2048): rows 2*i0, 2*i0+1 sumsq; threefry rows i0 and i0+2048.
__global__ void k_prep(const float* __restrict__ F, const int* __restrict__ labels,
                       float* __restrict__ sq, int* __restrict__ neg_idx,
                       float* __restrict__ acc) {
    int i0 = blockIdx.x;
    int t = threadIdx.x, w = t >> 6, lane = t & 63;
    if (i0 == 0 && t < 4) acc[t] = 0.f;  // [0]=sum, [1]=count, [2]=done-counter(bits), [3]=pad

    // sum-squares: waves 0,1 -> rows 2*i0, 2*i0+1
    if (w < 2) {
        int r = 2 * i0 + w;
        const float4* fr = (const float4*)(F + (size_t)r * D);
        float4 a = fr[lane * 2], b = fr[lane * 2 + 1];
        float s = a.x*a.x + a.y*a.y + a.z*a.z + a.w*a.w
                + b.x*b.x + b.y*b.y + b.z*b.z + b.w*b.w;
        for (int m = 32; m; m >>= 1) s += __shfl_xor(s, m, 64);
        if (lane == 0) sq[r] = s;
    }

    // threefry argmax for rows i0 (out0) and i0+2048 (out1)
    int lab0 = labels[i0], lab1 = labels[i0 + 2048];
    uint32_t v0 = 0u, v1 = 0u;
    int j0 = 0x7fffffff, j1 = 0x7fffffff;
    bool h0 = false, h1 = false;
    for (int j = t; j < N; j += 256) {
        uint32_t p = (uint32_t)(i0 * N + j);
        uint32_t x0 = p, x1 = p + NHALF;
        threefry2x32_01(x0, x1);
        uint32_t b0 = x0 >> 9, b1 = x1 >> 9;   // 23-bit draw, monotone in gumbel
        int lj = labels[j];
        if (lj != lab0) { if (!h0 || b0 > v0) { v0 = b0; j0 = j; h0 = true; } }
        if (lj != lab1) { if (!h1 || b1 > v1) { v1 = b1; j1 = j; h1 = true; } }
    }
    for (int m = 32; m; m >>= 1) {
        uint32_t ov = __shfl_xor(v0, m, 64); int oj = __shfl_xor(j0, m, 64);
        argmax_combine(v0, j0, ov, oj);
        ov = __shfl_xor(v1, m, 64); oj = __shfl_xor(j1, m, 64);
        argmax_combine(v1, j1, ov, oj);
    }
    __shared__ uint32_t sv0[4], sv1[4];
    __shared__ int sj0[4], sj1[4];
    if (lane == 0) { sv0[w] = v0; sj0[w] = j0; sv1[w] = v1; sj1[w] = j1; }
    __syncthreads();
    if (t == 0) {
        uint32_t bv = sv0[0]; int bj = sj0[0];
        for (int k = 1; k < 4; k++) argmax_combine(bv, bj, sv0[k], sj0[k]);
        neg_idx[i0] = (bj == 0x7fffffff) ? -1 : bj;
        bv = sv1[0]; bj = sj1[0];
        for (int k = 1; k < 4; k++) argmax_combine(bv, bj, sv1[k], sj1[k]);
        neg_idx[i0 + 2048] = (bj == 0x7fffffff) ? -1 : bj;
    }
}

// K2 (fused): one block per label — scan labels into bucket, sort, inline
// neg_dist per anchor, enumerate pairs, accumulate, last-block finalize.
__global__ void k_pairs(const float* __restrict__ F, const int* __restrict__ labels,
                        const float* __restrict__ sq, const int* __restrict__ neg_idx,
                        float* __restrict__ acc, float* __restrict__ out) {
    int l = blockIdx.x;
    int t = threadIdx.x, w = t >> 6, lane = t & 63;
    __shared__ int rows[MAXB];
    __shared__ float ndist[MAXB];
    __shared__ int ccnt;
    __shared__ float wtot[4];
    __shared__ int wcnt[4];

    if (t == 0) ccnt = 0;
    __syncthreads();
    for (int j = t; j < N; j += 256) {
        if (labels[j] == l) {
            int p = atomicAdd(&ccnt, 1);
            if (p < MAXB) rows[p] = j;
        }
    }
    __syncthreads();
    int c = min(ccnt, MAXB);

    float tot = 0.f; int cnt = 0;
    if (c >= 2) {
        // sort ascending (tiny c) so anchor of pair (a,b), a<b is rows[a]
        if (t == 0) {
            for (int a = 1; a < c; a++) {
                int key = rows[a]; int b = a - 1;
                while (b >= 0 && rows[b] > key) { rows[b + 1] = rows[b]; b--; }
                rows[b + 1] = key;
            }
        }
        __syncthreads();
        // neg_dist per row, distributed across waves
        for (int a = w; a < c; a += 4) {
            int r = rows[a];
            int jn = neg_idx[r];
            float nd = 0.f;
            if (jn >= 0) {
                float d = wave_dot((const float4*)(F + (size_t)r * D),
                                   (const float4*)(F + (size_t)jn * D), lane);
                nd = sqrtf(fmaxf(sq[r] + sq[jn] - 2.f * d, EPS_F));
            }
            if (lane == 0) ndist[a] = nd;
        }
        __syncthreads();
        // pairs round-robin across waves
        int pidx = 0;
        for (int a = 0; a < c - 1; a++) {
            int ra = rows[a];
            bool hasneg = neg_idx[ra] >= 0;
            float nd = ndist[a];
            float sqa = sq[ra];
            const float4* fa = (const float4*)(F + (size_t)ra * D);
            for (int b = a + 1; b < c; b++, pidx++) {
                if ((pidx & 3) != w) continue;      // wave-uniform
                if (!hasneg) continue;
                int rb = rows[b];
                float d = wave_dot(fa, (const float4*)(F + (size_t)rb * D), lane);
                float dist = sqrtf(fmaxf(sqa + sq[rb] - 2.f * d, EPS_F));
                tot += fmaxf(MARGIN_F + dist - nd, 0.f);
                cnt++;
            }
        }
    }
    if (lane == 0) { wtot[w] = tot; wcnt[w] = cnt; }
    __syncthreads();
    if (t == 0) {
        float T = wtot[0] + wtot[1] + wtot[2] + wtot[3];
        int   C = wcnt[0] + wcnt[1] + wcnt[2] + wcnt[3];
        if (C > 0) {
            atomicAdd(&acc[0], T);
            atomicAdd(&acc[1], (float)C);
        }
        __threadfence();
        unsigned done = atomicAdd((unsigned*)&acc[2], 1u);
        if (done == (unsigned)(gridDim.x - 1)) {
            // device-scope atomic reads: plain loads could hit a stale L1 line
            float s = atomicAdd(&acc[0], 0.0f);
            float k = atomicAdd(&acc[1], 0.0f);
            out[0] = (k > 0.f) ? (s / k) : 0.f;
        }
    }
}

extern "C" void kernel_launch(void* const* d_in, const int* in_sizes, int n_in,
                              void* d_out, int out_size, void* d_ws, size_t ws_size,
                              hipStream_t stream) {
    const float* F      = (const float*)d_in[0];
    const int*   labels = (const int*)d_in[1];
    float* out = (float*)d_out;

    float* sq      = (float*)d_ws;                    // 4096 f @ 0
    int*   neg_idx = (int*)((char*)d_ws + 16384);     // 4096 i @ 16K
    float* acc     = (float*)((char*)d_ws + 32768);   // 4 f    @ 32K

    k_prep <<<N / 2, 256, 0, stream>>>(F, labels, sq, neg_idx, acc);
    k_pairs<<<L,     256, 0, stream>>>(F, labels, sq, neg_idx, acc, out);
}